// Round 4
// baseline (157.139 us; speedup 1.0000x reference)
//
#include <hip/hip_runtime.h>
#include <hip/hip_bf16.h>
#include <math.h>

// HIR rainfall-runoff scan — tolerance-bracketed time-chunking + exact fixup.
//
// V5 changes vs V4 (145.9 us; pass1t 44.7 us, ~95 us in fixup/transposes/gaps):
//  * pass1t was dep-latency bound at 1 wave/SIMD (VALUBusy ~50% == the
//    single-wave dependent-chain issue ceiling: 2 cy issue vs ~4 cy latency).
//    Fix: lane-pair the warm-up bracket chains — even lane hi(+gw), odd lane
//    lo, SAME stepw code path (no divergence), merged via shfl_xor. 2*B*NC
//    threads -> 2048 waves = 2 waves/SIMD -> warm-up (~85% of work) runs at
//    ~full issue density. Main chunk redundant on both lanes (same wave-time),
//    even lane stores. Bit-identical numerics to V4. (V3's pairing regression
//    was the single-address atomicAdd funnel, fixed since by build_queue.)
//  * W 320 -> 384: bracket gap shrinks x0.28 (contraction ~0.0201/step) ->
//    expected gap ~0.2 vs MERGE_TOL 0.75. Collapses the unmerged tail that
//    made fixup ~55-70 us in V4. Chunks 0..5 now exact.
//  * qcount zeroed by transpose_in thread (0,0,0) — memset dispatch dropped.
//
// Q[b,t] (t>=1) = fluxes from carry entering step t; Q[b,0] uses the FINAL
// carry (jnp.roll wraparound) with t=0 inputs (chunk NC-1 owner writes it).

struct P {
    float INSC, SMSC, RecK, g1, lc, k1, k2, k3, c2;
    // g1=1-RecK, lc=log2(COEFF), k1=SUB/SMSC, k2=CRAK/SMSC, k3=10/SMSC,
    // c2=-SQ/SMSC*log2(e)
};

__device__ __forceinline__ P make_params(const float* pINSC, const float* pCOEFF,
                                         const float* pSQ,   const float* pSMSC,
                                         const float* pSUB,  const float* pCRAK,
                                         const float* pRecK) {
    P p;
    p.INSC      = fminf(fmaxf(pINSC[0]  * 5.0f,   0.5f),   5.0f);
    float COEFF = fminf(fmaxf(pCOEFF[0] * 400.0f, 50.0f),  400.0f);
    float SQ    = fminf(fmaxf(pSQ[0]    * 6.0f,   0.0f),   6.0f);
    p.SMSC      = fminf(fmaxf(pSMSC[0]  * 500.0f, 50.0f),  500.0f);
    float SUB   = fminf(fmaxf(pSUB[0],  0.0f), 1.0f);
    float CRAK  = fminf(fmaxf(pCRAK[0], 0.0f), 1.0f);
    p.RecK      = fminf(fmaxf(pRecK[0]  * 0.3f,   0.003f), 0.3f);
    p.g1 = 1.0f - p.RecK;
    p.lc = log2f(COEFF);
    float inv = 1.0f / p.SMSC;
    p.k1 = SUB * inv;
    p.k2 = CRAK * inv;
    p.k3 = 10.0f * inv;
    p.c2 = (-SQ * inv) * 1.44269504088896340736f;
    return p;
}

// Full step with Q. Critical sms chain: fminf -> fmaf -> exp2f -> fminf ->
// mul -> fmaf. Everything else is off-path.
__device__ __forceinline__ float step(float Prec, float PET, float& sms, float& gw, const P& p) {
    float INT  = fminf(fminf(p.INSC, PET), Prec);
    float INR  = Prec - INT;
    float POT  = PET - INT;
    float S    = fminf(sms, p.SMSC);                 // lower clamp provably slack
    float u    = fmaf(-p.k1, S, 1.0f);
    float v    = fmaf(-p.k2, S, 1.0f);
    float ETS  = fminf(POT, p.k3 * S);
    float SmE  = S - ETS;
    float e    = exp2f(fmaf(p.c2, S, p.lc));         // cap = COEFF*2^(c2*S)
    float RMO  = fminf(INR, e);
    float w    = u * RMO;                            // t2 = RMO - SRUN
    float s2   = fmaf(v, w, SmE);                    // S + SMF - ETS
    float SMF  = v * w;
    float REC  = w - SMF;
    float RECnew = REC + fmaxf(s2 - p.SMSC, 0.0f);
    float BAS  = p.RecK * gw;
    float Q    = (INR - w) + BAS;                    // IRUN + SRUN + BAS
    gw  = fmaf(p.g1, gw, RECnew);
    sms = s2;
    return Q;
}

// Warm-up / state-advance step without Q (single chain, carries gw).
// sms update never reads gw, so a lane carrying a bracket sms-chain can run
// this unchanged (its gw output is simply discarded).
__device__ __forceinline__ void stepw(float Prec, float PET, float& sms, float& gw, const P& p) {
    float INT  = fminf(fminf(p.INSC, PET), Prec);
    float INR  = Prec - INT;
    float POT  = PET - INT;
    float S    = fminf(sms, p.SMSC);
    float u    = fmaf(-p.k1, S, 1.0f);
    float v    = fmaf(-p.k2, S, 1.0f);
    float ETS  = fminf(POT, p.k3 * S);
    float SmE  = S - ETS;
    float e    = exp2f(fmaf(p.c2, S, p.lc));
    float RMO  = fminf(INR, e);
    float w    = u * RMO;
    float s2   = fmaf(v, w, SmE);
    float SMF  = v * w;
    float REC  = w - SMF;
    float RECnew = REC + fmaxf(s2 - p.SMSC, 0.0f);
    gw  = fmaf(p.g1, gw, RECnew);
    sms = s2;
}

// Dual-bracket warm-up step (legacy path only).
__device__ __forceinline__ void dstep(float Prec, float PET,
                                      float& slo, float& shi, float& gw, const P& p) {
    float INT = fminf(fminf(p.INSC, PET), Prec);
    float INR = Prec - INT;
    float POT = PET - INT;
    {   // hi + gw
        float S    = fminf(shi, p.SMSC);
        float u    = fmaf(-p.k1, S, 1.0f);
        float v    = fmaf(-p.k2, S, 1.0f);
        float ETS  = fminf(POT, p.k3 * S);
        float SmE  = S - ETS;
        float e    = exp2f(fmaf(p.c2, S, p.lc));
        float RMO  = fminf(INR, e);
        float w    = u * RMO;
        float s2   = fmaf(v, w, SmE);
        float SMF  = v * w;
        float REC  = w - SMF;
        float RECnew = REC + fmaxf(s2 - p.SMSC, 0.0f);
        gw  = fmaf(p.g1, gw, RECnew);
        shi = s2;
    }
    {   // lo, sms only
        float S    = fminf(slo, p.SMSC);
        float u    = fmaf(-p.k1, S, 1.0f);
        float v    = fmaf(-p.k2, S, 1.0f);
        float ETS  = fminf(POT, p.k3 * S);
        float SmE  = S - ETS;
        float e    = exp2f(fmaf(p.c2, S, p.lc));
        float RMO  = fminf(INR, e);
        float w    = u * RMO;
        slo = fmaf(v, w, SmE);
    }
}

#define MERGE_TOL 0.75f

// ---------------------------------------------------------------------------
// Transposes: inputs[b][t] (float2 Prec,PET) -> tp[t][b];  qtp[t][b] -> out[b][t]
// transpose_in also zeroes qcount (stream-ordered before build_queue).
// ---------------------------------------------------------------------------

__global__ __launch_bounds__(256)
void transpose_in(const float2* __restrict__ in, float2* __restrict__ tp,
                  unsigned int* __restrict__ qcount, int B, int Tdim)
{
    if (blockIdx.x == 0 && blockIdx.y == 0 && threadIdx.x == 0) *qcount = 0u;
    __shared__ float2 tile[64][65];
    int t0 = blockIdx.x * 64, b0 = blockIdx.y * 64;
    int l = threadIdx.x & 63, w = threadIdx.x >> 6;
    #pragma unroll
    for (int j = 0; j < 16; ++j) {
        int bb = w * 16 + j;
        tile[l][bb] = in[(long)(b0 + bb) * Tdim + t0 + l];   // coalesced along t
    }
    __syncthreads();
    #pragma unroll
    for (int j = 0; j < 16; ++j) {
        int tt = w * 16 + j;
        tp[(long)(t0 + tt) * B + b0 + l] = tile[tt][l];      // coalesced along b
    }
}

__global__ __launch_bounds__(256)
void transpose_out(const float* __restrict__ qtp, float* __restrict__ out,
                   int B, int Tdim)
{
    __shared__ float tile[64][65];
    int t0 = blockIdx.x * 64, b0 = blockIdx.y * 64;
    int l = threadIdx.x & 63, w = threadIdx.x >> 6;
    #pragma unroll
    for (int j = 0; j < 16; ++j) {
        int tt = w * 16 + j;
        tile[tt][l] = qtp[(long)(t0 + tt) * B + b0 + l];     // coalesced along b
    }
    __syncthreads();
    #pragma unroll
    for (int j = 0; j < 16; ++j) {
        int bb = w * 16 + j;
        out[(long)(b0 + bb) * Tdim + t0 + l] = tile[l][bb];  // coalesced along t
    }
}

// ---------------------------------------------------------------------------
// Pass 1 (time-major, lane-paired brackets): thread pair (2k,2k+1) shares
// (b,c). Even lane: hi bracket chain + gw. Odd lane: lo chain (gw discarded).
// One uniform stepw path; merge via shfl_xor. 2*B*NC threads = 2 waves/SIMD.
// Wave loads tp[t*B+b] cover 32 consecutive b (pairs broadcast) = 256 B.
// ---------------------------------------------------------------------------

template<int T, int NC, int W>
__global__ __launch_bounds__(64, 1)
void hir_pass1t(const float2* __restrict__ tp,
                const float* __restrict__ pINSC,  const float* __restrict__ pCOEFF,
                const float* __restrict__ pSQ,    const float* __restrict__ pSMSC,
                const float* __restrict__ pSUB,   const float* __restrict__ pCRAK,
                const float* __restrict__ pRecK,
                float* __restrict__ qtp, float4* __restrict__ st, int B)
{
    int gid = blockIdx.x * blockDim.x + threadIdx.x;
    int h  = gid & 1;            // 0 = hi chain (+gw, stores), 1 = lo chain
    int pb = gid >> 1;
    int b = pb % B;              // pair-consecutive columns
    int c = pb / B;              // wave-uniform (B % 32 == 0)
    if (c >= NC) return;

    P p = make_params(pINSC, pCOEFF, pSQ, pSMSC, pSUB, pCRAK, pRecK);

    const float2* __restrict__ col = tp + b;   // element t at col[(long)t*B]

    constexpr int CH = T / NC;             // 64 steps
    const int t1 = c * CH;
    int t0 = t1 - W;
    const bool exact = (t0 <= 0);
    if (t0 < 0) t0 = 0;

    // exact: both lanes run the true chain from 0 (identical values).
    float s  = exact ? 0.0f : (h ? 0.0f : p.SMSC);
    float gw = 0.0f;

    // ---- Warm-up: depth-2 pipeline of 8-step batches, one chain per lane ----
    const int nwb = (t1 - t0) >> 3;        // (t1-t0) is a multiple of 8
    if (nwb > 0) {
        float2 A[8], Bq[8], C[8];
        #pragma unroll
        for (int j = 0; j < 8; ++j) A[j] = col[(long)(t0 + j) * B];
        {
            int tB = t0 + ((1 < nwb) ? 8 : 0);
            #pragma unroll
            for (int j = 0; j < 8; ++j) Bq[j] = col[(long)(tB + j) * B];
        }
        for (int k = 0; k < nwb; ++k) {
            int kn = (k + 2 < nwb) ? (k + 2) : (nwb - 1);
            #pragma unroll
            for (int j = 0; j < 8; ++j) C[j] = col[(long)(t0 + 8 * kn + j) * B];
            #pragma unroll
            for (int j = 0; j < 8; ++j) stepw(A[j].x, A[j].y, s, gw, p);
            #pragma unroll
            for (int j = 0; j < 8; ++j) { A[j] = Bq[j]; Bq[j] = C[j]; }
        }
    }

    // ---- Pair exchange: bracket merge + gw broadcast from even lane ----
    float so = __shfl_xor(s, 1);
    float go = __shfl_xor(gw, 1);
    float shi = h ? so : s;
    float slo = h ? s : so;
    gw = h ? go : gw;                      // true-warmup gw lives on even lane
    const bool merged = exact || ((shi - slo) <= MERGE_TOL);
    float sms = 0.5f * (slo + shi);        // == s for exact chunks

    // ---- Main chunk: 64 steps, both lanes compute, even lane stores ----
    {
        constexpr int nmb = CH / 8;        // 8 batches
        float2 A[8], Bq[8], C[8];
        #pragma unroll
        for (int j = 0; j < 8; ++j) A[j] = col[(long)(t1 + j) * B];
        #pragma unroll
        for (int j = 0; j < 8; ++j) Bq[j] = col[(long)(t1 + 8 + j) * B];
        for (int k = 0; k < nmb; ++k) {
            int kn = (k + 2 < nmb) ? (k + 2) : (nmb - 1);
            #pragma unroll
            for (int j = 0; j < 8; ++j) C[j] = col[(long)(t1 + 8 * kn + j) * B];
            int tb = t1 + 8 * k;
            #pragma unroll
            for (int j = 0; j < 8; ++j) {
                float q = step(A[j].x, A[j].y, sms, gw, p);
                int t = tb + j;
                if (!h && !(c == 0 && t == 0)) {
                    qtp[(long)t * B + b] = q;      // t=0 owned by wraparound
                }
            }
            #pragma unroll
            for (int j = 0; j < 8; ++j) { A[j] = Bq[j]; Bq[j] = C[j]; }
        }
    }

    if (!h) {
        st[(size_t)c * B + b] = make_float4(sms, gw, merged ? 1.0f : 0.0f, 0.0f);
        if (c == NC - 1) {                 // Q[b,0] from final carry (roll)
            float2 f0 = col[0];
            float ss = sms, gg = gw;
            qtp[b] = step(f0.x, f0.y, ss, gg, p);
        }
    }
}

// ---------------------------------------------------------------------------
// Queue build: wave ballot-compaction, ONE atomicAdd per wave (<=1024 total).
// Item encoding: gid = c*B + b (st's linear index).
// ---------------------------------------------------------------------------

__global__ __launch_bounds__(64)
void build_queue(const float4* __restrict__ st, unsigned int* __restrict__ qcount,
                 unsigned int* __restrict__ qitems, int n)
{
    int gid = blockIdx.x * blockDim.x + threadIdx.x;
    bool un = false;
    if (gid < n) un = (st[gid].z == 0.0f);
    unsigned long long mask = __ballot(un);
    int lane = threadIdx.x;                // blockDim == 64 == one wave
    int cnt = __popcll(mask);
    unsigned int base = 0;
    if (lane == 0 && cnt) base = atomicAdd(qcount, (unsigned int)cnt);
    base = (unsigned int)__shfl((int)base, 0);
    if (un) {
        int pre = __popcll(mask & ((1ull << lane) - 1ull));
        qitems[base + pre] = (unsigned int)gid;
    }
}

// ---------------------------------------------------------------------------
// Fixup over the dense unmerged-item queue. Reads the ORIGINAL [b][t] inputs
// (per-thread sequential float4s, good L1 line reuse), writes qtp. Each item
// (b,c) walks back to the nearest merged predecessor m (chunk 0 always exact
// => merged), advances state store-free through m+1..c-1, then recomputes
// chunk c with stores. Same semantics as the sequential per-row fixup.
// ---------------------------------------------------------------------------

template<int T, int NC>
__global__ __launch_bounds__(64)
void hir_fixup(const float* __restrict__ inputs,
               const float* __restrict__ pINSC,  const float* __restrict__ pCOEFF,
               const float* __restrict__ pSQ,    const float* __restrict__ pSMSC,
               const float* __restrict__ pSUB,   const float* __restrict__ pCRAK,
               const float* __restrict__ pRecK,
               float* __restrict__ qtp, const float4* __restrict__ st,
               const unsigned int* __restrict__ qcount,
               const unsigned int* __restrict__ qitems, int B)
{
    int gid = blockIdx.x * blockDim.x + threadIdx.x;
    int stride = gridDim.x * blockDim.x;
    int n = (int)*qcount;

    P p = make_params(pINSC, pCOEFF, pSQ, pSMSC, pSUB, pCRAK, pRecK);
    constexpr int CH = T / NC;

    for (int it = gid; it < n; it += stride) {
        unsigned int item = qitems[it];
        int b = (int)(item % (unsigned int)B);
        int c = (int)(item / (unsigned int)B);

        const float4* __restrict__ rp = (const float4*)(inputs + (size_t)b * (2 * T));

        // Walk back to nearest merged predecessor (c >= 1: chunk 0 merged).
        int m = c - 1;
        float4 sm = st[(size_t)m * B + b];
        while (sm.z == 0.0f) { --m; sm = st[(size_t)m * B + b]; }
        float sms = sm.x, gw = sm.y;

        // Advance state through chunks m+1..c-1 (no stores).
        {
            const int ia = ((m + 1) * CH) >> 1;
            const int ib = (c * CH) >> 1;
            if (ia < ib) {
                float4 cur = rp[ia];
                for (int i = ia; i < ib; ++i) {
                    int ni = (i + 1 < ib) ? (i + 1) : i;
                    float4 nxt = rp[ni];
                    stepw(cur.x, cur.y, sms, gw, p);
                    stepw(cur.z, cur.w, sms, gw, p);
                    cur = nxt;
                }
            }
        }

        // Recompute chunk c exactly, with stores into qtp[t][b].
        {
            const int i1 = (c * CH) >> 1;
            const int i2 = ((c + 1) * CH) >> 1;
            float4 cur = rp[i1];
            for (int i = i1; i < i2; ++i) {
                int ni = (i + 1 < i2) ? (i + 1) : i;
                float4 nxt = rp[ni];
                float qa = step(cur.x, cur.y, sms, gw, p);
                float qb = step(cur.z, cur.w, sms, gw, p);
                qtp[(long)(2 * i) * B + b]     = qa;
                qtp[(long)(2 * i + 1) * B + b] = qb;
                cur = nxt;
            }
        }

        if (c == NC - 1) {                 // rewrite the t=0 wraparound output
            float4 f0 = rp[0];
            float ss = sms, gg = gw;
            qtp[b] = step(f0.x, f0.y, ss, gg, p);
        }
    }
}

// ---------------------------------------------------------------------------
// Legacy V2 path (fallback when workspace is small): scattered-load pass1 +
// sequential per-row pass2. Known-good at 120.8 us.
// ---------------------------------------------------------------------------

template<int T, int NC, int W>
__global__ __launch_bounds__(64, 1)
void hir_pass1_legacy(const float* __restrict__ inputs,
               const float* __restrict__ pINSC,  const float* __restrict__ pCOEFF,
               const float* __restrict__ pSQ,    const float* __restrict__ pSMSC,
               const float* __restrict__ pSUB,   const float* __restrict__ pCRAK,
               const float* __restrict__ pRecK,
               float* __restrict__ out, float4* __restrict__ st, int B)
{
    int gid = blockIdx.x * blockDim.x + threadIdx.x;
    int b = gid % B;
    int c = gid / B;
    if (c >= NC) return;

    P p = make_params(pINSC, pCOEFF, pSQ, pSMSC, pSUB, pCRAK, pRecK);

    const float4* __restrict__ rp = (const float4*)(inputs + (size_t)b * (2 * T));
    float* __restrict__ orow = out + (size_t)b * T;

    constexpr int CH = T / NC;
    const int i1 = (c * CH) >> 1;
    int i0 = i1 - (W >> 1);
    const bool exact = (i0 <= 0);
    if (i0 < 0) i0 = 0;

    float slo = 0.0f, shi = exact ? 0.0f : p.SMSC, gw = 0.0f;

    const int nwb = (i1 - i0) >> 2;
    if (nwb > 0) {
        float4 A[4], Bq[4], C[4];
        #pragma unroll
        for (int j = 0; j < 4; ++j) A[j] = rp[i0 + j];
        {
            int k1b = (1 < nwb) ? 1 : 0;
            #pragma unroll
            for (int j = 0; j < 4; ++j) Bq[j] = rp[i0 + 4 * k1b + j];
        }
        if (exact) {
            for (int k = 0; k < nwb; ++k) {
                int kn = (k + 2 < nwb) ? (k + 2) : (nwb - 1);
                #pragma unroll
                for (int j = 0; j < 4; ++j) C[j] = rp[i0 + 4 * kn + j];
                #pragma unroll
                for (int j = 0; j < 4; ++j) {
                    stepw(A[j].x, A[j].y, shi, gw, p);
                    stepw(A[j].z, A[j].w, shi, gw, p);
                }
                #pragma unroll
                for (int j = 0; j < 4; ++j) { A[j] = Bq[j]; Bq[j] = C[j]; }
            }
            slo = shi;
        } else {
            for (int k = 0; k < nwb; ++k) {
                int kn = (k + 2 < nwb) ? (k + 2) : (nwb - 1);
                #pragma unroll
                for (int j = 0; j < 4; ++j) C[j] = rp[i0 + 4 * kn + j];
                #pragma unroll
                for (int j = 0; j < 4; ++j) {
                    dstep(A[j].x, A[j].y, slo, shi, gw, p);
                    dstep(A[j].z, A[j].w, slo, shi, gw, p);
                }
                #pragma unroll
                for (int j = 0; j < 4; ++j) { A[j] = Bq[j]; Bq[j] = C[j]; }
            }
        }
    }
    const bool merged = exact || ((shi - slo) <= MERGE_TOL);
    float sms = exact ? shi : (0.5f * (slo + shi));

    {
        constexpr int nmb = (CH / 2) / 4;
        float4 A[4], Bq[4], C[4];
        #pragma unroll
        for (int j = 0; j < 4; ++j) A[j] = rp[i1 + j];
        #pragma unroll
        for (int j = 0; j < 4; ++j) Bq[j] = rp[i1 + 4 + j];
        for (int k = 0; k < nmb; ++k) {
            int kn = (k + 2 < nmb) ? (k + 2) : (nmb - 1);
            #pragma unroll
            for (int j = 0; j < 4; ++j) C[j] = rp[i1 + 4 * kn + j];
            int ibase = i1 + 4 * k;
            #pragma unroll
            for (int j = 0; j < 4; ++j) {
                float qa = step(A[j].x, A[j].y, sms, gw, p);
                float qb = step(A[j].z, A[j].w, sms, gw, p);
                if (c == 0 && k == 0 && j == 0) {
                    orow[1] = qb;
                } else {
                    ((float2*)orow)[ibase + j] = make_float2(qa, qb);
                }
            }
            #pragma unroll
            for (int j = 0; j < 4; ++j) { A[j] = Bq[j]; Bq[j] = C[j]; }
        }
    }

    st[(size_t)c * B + b] = make_float4(sms, gw, merged ? 1.0f : 0.0f, 0.0f);

    if (c == NC - 1) {
        float4 f0 = rp[0];
        float ss = sms, gg = gw;
        orow[0] = step(f0.x, f0.y, ss, gg, p);
    }
}

template<int T, int NC>
__global__ __launch_bounds__(64, 1)
void hir_pass2_legacy(const float* __restrict__ inputs,
               const float* __restrict__ pINSC,  const float* __restrict__ pCOEFF,
               const float* __restrict__ pSQ,    const float* __restrict__ pSMSC,
               const float* __restrict__ pSUB,   const float* __restrict__ pCRAK,
               const float* __restrict__ pRecK,
               float* __restrict__ out, const float4* __restrict__ st, int B)
{
    int b = blockIdx.x * blockDim.x + threadIdx.x;
    if (b >= B) return;

    P p = make_params(pINSC, pCOEFF, pSQ, pSMSC, pSUB, pCRAK, pRecK);
    constexpr int CH = T / NC;

    const float4* __restrict__ rp = (const float4*)(inputs + (size_t)b * (2 * T));
    float* __restrict__ orow = out + (size_t)b * T;

    float4 s0 = st[b];
    float ex_s = s0.x, ex_g = s0.y;

    for (int c = 1; c < NC; ++c) {
        float4 sc = st[(size_t)c * B + b];
        if (sc.z != 0.0f) {
            ex_s = sc.x; ex_g = sc.y;
            continue;
        }
        float sms = ex_s, gw = ex_g;
        const int i1 = (c * CH) >> 1;
        const int i2 = ((c + 1) * CH) >> 1;
        float4 cur = rp[i1];
        for (int i = i1; i < i2; ++i) {
            int ni = (i + 1 < i2) ? (i + 1) : i;
            float4 nxt = rp[ni];
            float qa = step(cur.x, cur.y, sms, gw, p);
            float qb = step(cur.z, cur.w, sms, gw, p);
            ((float2*)orow)[i] = make_float2(qa, qb);
            cur = nxt;
        }
        ex_s = sms; ex_g = gw;
        if (c == NC - 1) {
            float4 f0 = rp[0];
            float ss = sms, gg = gw;
            orow[0] = step(f0.x, f0.y, ss, gg, p);
        }
    }
}

// Fallback: monolithic sequential (odd shapes / tiny workspace).
template<int T>
__global__ __launch_bounds__(64, 1)
void hir_scan_kernel(const float* __restrict__ inputs,
                     const float* __restrict__ pINSC,  const float* __restrict__ pCOEFF,
                     const float* __restrict__ pSQ,    const float* __restrict__ pSMSC,
                     const float* __restrict__ pSUB,   const float* __restrict__ pCRAK,
                     const float* __restrict__ pRecK,
                     float* __restrict__ out, int B)
{
    int b = blockIdx.x * blockDim.x + threadIdx.x;
    if (b >= B) return;
    P p = make_params(pINSC, pCOEFF, pSQ, pSMSC, pSUB, pCRAK, pRecK);
    const float4* __restrict__ rp = (const float4*)(inputs + (size_t)b * (2 * T));
    float* __restrict__ orow = out + (size_t)b * T;
    float sms = 0.0f, gw = 0.0f;
    float4 cur = rp[0];
    const float P0 = cur.x, E0 = cur.y;
    constexpr int NI = T / 2;
    for (int i = 0; i < NI; ++i) {
        int ni = (i + 1 < NI) ? (i + 1) : i;
        float4 nxt = rp[ni];
        float qa = step(cur.x, cur.y, sms, gw, p);
        float qb = step(cur.z, cur.w, sms, gw, p);
        if (i == 0) { orow[1] = qb; }
        else        { ((float2*)orow)[i] = make_float2(qa, qb); }
        cur = nxt;
    }
    float ss = sms, gg = gw;
    orow[0] = step(P0, E0, ss, gg, p);
}

extern "C" void kernel_launch(void* const* d_in, const int* in_sizes, int n_in,
                              void* d_out, int out_size, void* d_ws, size_t ws_size,
                              hipStream_t stream) {
    (void)n_in; (void)out_size;
    constexpr int T  = 1024;
    constexpr int NC = 16;    // chunks (CH=64)
    constexpr int W  = 384;   // warm-up steps: gap ~450*e^(-.0201*384)~0.2 << 0.75
    const float* inputs = (const float*)d_in[0];
    const float* INSC   = (const float*)d_in[1];
    const float* COEFF  = (const float*)d_in[2];
    const float* SQ     = (const float*)d_in[3];
    const float* SMSC   = (const float*)d_in[4];
    const float* SUB    = (const float*)d_in[5];
    const float* CRAK   = (const float*)d_in[6];
    const float* RecK   = (const float*)d_in[7];
    float* out = (float*)d_out;

    int B = in_sizes[0] / (2 * T);            // 4096 for the reference shape
    size_t tpBytes  = (size_t)B * T * sizeof(float2);   // 32 MB
    size_t qtpBytes = (size_t)B * T * sizeof(float);    // 16 MB
    size_t stBytes  = (size_t)B * NC * sizeof(float4);  //  1 MB
    size_t qBytes   = (size_t)B * NC * sizeof(unsigned int);
    size_t bigNeed  = tpBytes + qtpBytes + stBytes + 64 + qBytes;

    if ((B % 64) == 0 && ws_size >= bigNeed) {
        // ---- Time-major pipeline ----
        float2* tp = (float2*)d_ws;
        float*  qtp = (float*)((char*)d_ws + tpBytes);
        float4* st  = (float4*)((char*)d_ws + tpBytes + qtpBytes);
        unsigned int* qcount = (unsigned int*)((char*)d_ws + tpBytes + qtpBytes + stBytes);
        unsigned int* qitems = (unsigned int*)((char*)d_ws + tpBytes + qtpBytes + stBytes + 64);

        transpose_in<<<dim3(T / 64, B / 64), dim3(256), 0, stream>>>(
            (const float2*)inputs, tp, qcount, B, T);

        long total = 2L * B * NC;             // 131072 threads = 2048 waves
        int blocks1 = (int)((total + 63) / 64);
        hir_pass1t<T, NC, W><<<dim3(blocks1), dim3(64), 0, stream>>>(
            tp, INSC, COEFF, SQ, SMSC, SUB, CRAK, RecK, qtp, st, B);

        int nst = B * NC;                     // st entries
        build_queue<<<dim3((nst + 63) / 64), dim3(64), 0, stream>>>(
            st, qcount, qitems, nst);

        hir_fixup<T, NC><<<dim3(1024), dim3(64), 0, stream>>>(
            inputs, INSC, COEFF, SQ, SMSC, SUB, CRAK, RecK, qtp, st, qcount, qitems, B);

        transpose_out<<<dim3(T / 64, B / 64), dim3(256), 0, stream>>>(
            qtp, out, B, T);
        return;
    }

    if ((B % 64) == 0 && ws_size >= stBytes) {
        // ---- Legacy V2 path ----
        float4* st = (float4*)d_ws;
        long total = (long)B * NC;
        int blocks1 = (int)((total + 63) / 64);
        hir_pass1_legacy<T, NC, W><<<dim3(blocks1), dim3(64), 0, stream>>>(
            inputs, INSC, COEFF, SQ, SMSC, SUB, CRAK, RecK, out, st, B);
        int blocks2 = (B + 63) / 64;
        hir_pass2_legacy<T, NC><<<dim3(blocks2), dim3(64), 0, stream>>>(
            inputs, INSC, COEFF, SQ, SMSC, SUB, CRAK, RecK, out, st, B);
        return;
    }

    int blocks = (B + 63) / 64;
    hir_scan_kernel<T><<<dim3(blocks), dim3(64), 0, stream>>>(
        inputs, INSC, COEFF, SQ, SMSC, SUB, CRAK, RecK, out, B);
}

// Round 5
// 123.850 us; speedup vs baseline: 1.2688x; 1.2688x over previous
//
#include <hip/hip_runtime.h>
#include <hip/hip_bf16.h>
#include <math.h>

// HIR rainfall-runoff scan — tolerance-bracketed time-chunking + exact fixup.
//
// V6: minimum-kernel rebuild from measured components.
//  * Post-mortems: V5 lane-pairing issued 1.8x the instructions for the same
//    output (22.4 -> 40.2 us of issue) — reverted to V2/V4's single-thread
//    dstep warm-up. V4/V5 showed aux cost (transposes + 5 dispatches) is a
//    constant ~100 us while fixup was always cheap (SMSC=250 -> V4 gap ~0.4
//    already merged); transpose_in spent >=56 us to save 7.3 us of pass1
//    load stalls. All staging/queue kernels deleted.
//  * 2 kernels total:
//    - hir_pass1: V2's proven loop (scattered float4 row loads, depth-2
//      pipeline, dstep bracket warm-up, W=384) + fused LDS store-transpose:
//      Q -> lds_q[t][lane] (bank-free), then a store phase emits 256 B
//      coalesced wave-stores out[b0+j][t1+l]. Removes the 64-line scattered
//      stores from the hot loop; costs 16.6 KB LDS (no occupancy impact).
//    - hir_fixup: thread per (b,c), early-exit if merged (one coalesced st
//      read). Rare unmerged items recompute exactly from the nearest merged
//      predecessor and write out rows directly. No queue/atomics/memset.
//
// Q[b,t] (t>=1) = fluxes from carry entering step t; Q[b,0] uses the FINAL
// carry (jnp.roll wraparound) with t=0 inputs (chunk NC-1 owner writes it).

struct P {
    float INSC, SMSC, RecK, g1, lc, k1, k2, k3, c2;
    // g1=1-RecK, lc=log2(COEFF), k1=SUB/SMSC, k2=CRAK/SMSC, k3=10/SMSC,
    // c2=-SQ/SMSC*log2(e)
};

__device__ __forceinline__ P make_params(const float* pINSC, const float* pCOEFF,
                                         const float* pSQ,   const float* pSMSC,
                                         const float* pSUB,  const float* pCRAK,
                                         const float* pRecK) {
    P p;
    p.INSC      = fminf(fmaxf(pINSC[0]  * 5.0f,   0.5f),   5.0f);
    float COEFF = fminf(fmaxf(pCOEFF[0] * 400.0f, 50.0f),  400.0f);
    float SQ    = fminf(fmaxf(pSQ[0]    * 6.0f,   0.0f),   6.0f);
    p.SMSC      = fminf(fmaxf(pSMSC[0]  * 500.0f, 50.0f),  500.0f);
    float SUB   = fminf(fmaxf(pSUB[0],  0.0f), 1.0f);
    float CRAK  = fminf(fmaxf(pCRAK[0], 0.0f), 1.0f);
    p.RecK      = fminf(fmaxf(pRecK[0]  * 0.3f,   0.003f), 0.3f);
    p.g1 = 1.0f - p.RecK;
    p.lc = log2f(COEFF);
    float inv = 1.0f / p.SMSC;
    p.k1 = SUB * inv;
    p.k2 = CRAK * inv;
    p.k3 = 10.0f * inv;
    p.c2 = (-SQ * inv) * 1.44269504088896340736f;
    return p;
}

// Full step with Q. Critical sms chain: fminf -> fmaf -> exp2f -> fminf ->
// mul -> fmaf. Everything else is off-path.
__device__ __forceinline__ float step(float Prec, float PET, float& sms, float& gw, const P& p) {
    float INT  = fminf(fminf(p.INSC, PET), Prec);
    float INR  = Prec - INT;
    float POT  = PET - INT;
    float S    = fminf(sms, p.SMSC);                 // lower clamp provably slack
    float u    = fmaf(-p.k1, S, 1.0f);
    float v    = fmaf(-p.k2, S, 1.0f);
    float ETS  = fminf(POT, p.k3 * S);
    float SmE  = S - ETS;
    float e    = exp2f(fmaf(p.c2, S, p.lc));         // cap = COEFF*2^(c2*S)
    float RMO  = fminf(INR, e);
    float w    = u * RMO;                            // t2 = RMO - SRUN
    float s2   = fmaf(v, w, SmE);                    // S + SMF - ETS
    float SMF  = v * w;
    float REC  = w - SMF;
    float RECnew = REC + fmaxf(s2 - p.SMSC, 0.0f);
    float BAS  = p.RecK * gw;
    float Q    = (INR - w) + BAS;                    // IRUN + SRUN + BAS
    gw  = fmaf(p.g1, gw, RECnew);
    sms = s2;
    return Q;
}

// Warm-up / state-advance step without Q (single chain, carries gw).
__device__ __forceinline__ void stepw(float Prec, float PET, float& sms, float& gw, const P& p) {
    float INT  = fminf(fminf(p.INSC, PET), Prec);
    float INR  = Prec - INT;
    float POT  = PET - INT;
    float S    = fminf(sms, p.SMSC);
    float u    = fmaf(-p.k1, S, 1.0f);
    float v    = fmaf(-p.k2, S, 1.0f);
    float ETS  = fminf(POT, p.k3 * S);
    float SmE  = S - ETS;
    float e    = exp2f(fmaf(p.c2, S, p.lc));
    float RMO  = fminf(INR, e);
    float w    = u * RMO;
    float s2   = fmaf(v, w, SmE);
    float SMF  = v * w;
    float REC  = w - SMF;
    float RECnew = REC + fmaxf(s2 - p.SMSC, 0.0f);
    gw  = fmaf(p.g1, gw, RECnew);
    sms = s2;
}

// Dual-bracket warm-up step: hi chain carries gw; lo chain is sms-only.
// Shares INT/INR/POT between the chains (the V5 pairing lost this).
__device__ __forceinline__ void dstep(float Prec, float PET,
                                      float& slo, float& shi, float& gw, const P& p) {
    float INT = fminf(fminf(p.INSC, PET), Prec);
    float INR = Prec - INT;
    float POT = PET - INT;
    {   // hi + gw
        float S    = fminf(shi, p.SMSC);
        float u    = fmaf(-p.k1, S, 1.0f);
        float v    = fmaf(-p.k2, S, 1.0f);
        float ETS  = fminf(POT, p.k3 * S);
        float SmE  = S - ETS;
        float e    = exp2f(fmaf(p.c2, S, p.lc));
        float RMO  = fminf(INR, e);
        float w    = u * RMO;
        float s2   = fmaf(v, w, SmE);
        float SMF  = v * w;
        float REC  = w - SMF;
        float RECnew = REC + fmaxf(s2 - p.SMSC, 0.0f);
        gw  = fmaf(p.g1, gw, RECnew);
        shi = s2;
    }
    {   // lo, sms only
        float S    = fminf(slo, p.SMSC);
        float u    = fmaf(-p.k1, S, 1.0f);
        float v    = fmaf(-p.k2, S, 1.0f);
        float ETS  = fminf(POT, p.k3 * S);
        float SmE  = S - ETS;
        float e    = exp2f(fmaf(p.c2, S, p.lc));
        float RMO  = fminf(INR, e);
        float w    = u * RMO;
        slo = fmaf(v, w, SmE);
    }
}

#define MERGE_TOL 0.75f

// ---------------------------------------------------------------------------
// Pass 1: one thread per (b, c); lanes = 64 consecutive b, c wave-uniform.
// V2's load/compute structure; Q buffered in LDS and written coalesced.
// ---------------------------------------------------------------------------

template<int T, int NC, int W>
__global__ __launch_bounds__(64, 1)
void hir_pass1(const float* __restrict__ inputs,
               const float* __restrict__ pINSC,  const float* __restrict__ pCOEFF,
               const float* __restrict__ pSQ,    const float* __restrict__ pSMSC,
               const float* __restrict__ pSUB,   const float* __restrict__ pCRAK,
               const float* __restrict__ pRecK,
               float* __restrict__ out, float4* __restrict__ st, int B)
{
    __shared__ float lds_q[64][65];        // [t_local][lane], +1 pad: bank-free
    const int l   = threadIdx.x;
    const int gid = blockIdx.x * 64 + l;
    const int b = gid % B;                 // consecutive lanes -> consecutive rows
    const int c = gid / B;                 // wave-uniform (B % 64 == 0)
    if (c >= NC) return;                   // never taken for the exact grid

    P p = make_params(pINSC, pCOEFF, pSQ, pSMSC, pSUB, pCRAK, pRecK);

    const float4* __restrict__ rp = (const float4*)(inputs + (size_t)b * (2 * T));
    float* __restrict__ orow = out + (size_t)b * T;

    constexpr int CH = T / NC;             // 64 steps
    const int i1 = (c * CH) >> 1;          // first main float4 index
    int i0 = i1 - (W >> 1);                // warm-up start (W/2 float4s)
    const bool exact = (i0 <= 0);
    if (i0 < 0) i0 = 0;

    float slo = 0.0f, shi = exact ? 0.0f : p.SMSC, gw = 0.0f;

    // ---- Warm-up: depth-2 pipeline of 4-float4 batches (8 steps each) ----
    const int nwb = (i1 - i0) >> 2;        // warm-up batches (count % 4 == 0)
    if (nwb > 0) {
        float4 A[4], Bq[4], C[4];
        #pragma unroll
        for (int j = 0; j < 4; ++j) A[j] = rp[i0 + j];
        {
            int k1b = (1 < nwb) ? 1 : 0;
            #pragma unroll
            for (int j = 0; j < 4; ++j) Bq[j] = rp[i0 + 4 * k1b + j];
        }
        if (exact) {
            for (int k = 0; k < nwb; ++k) {
                int kn = (k + 2 < nwb) ? (k + 2) : (nwb - 1);
                #pragma unroll
                for (int j = 0; j < 4; ++j) C[j] = rp[i0 + 4 * kn + j];
                #pragma unroll
                for (int j = 0; j < 4; ++j) {
                    stepw(A[j].x, A[j].y, shi, gw, p);
                    stepw(A[j].z, A[j].w, shi, gw, p);
                }
                #pragma unroll
                for (int j = 0; j < 4; ++j) { A[j] = Bq[j]; Bq[j] = C[j]; }
            }
            slo = shi;
        } else {
            for (int k = 0; k < nwb; ++k) {
                int kn = (k + 2 < nwb) ? (k + 2) : (nwb - 1);
                #pragma unroll
                for (int j = 0; j < 4; ++j) C[j] = rp[i0 + 4 * kn + j];
                #pragma unroll
                for (int j = 0; j < 4; ++j) {
                    dstep(A[j].x, A[j].y, slo, shi, gw, p);
                    dstep(A[j].z, A[j].w, slo, shi, gw, p);
                }
                #pragma unroll
                for (int j = 0; j < 4; ++j) { A[j] = Bq[j]; Bq[j] = C[j]; }
            }
        }
    }
    const bool merged = exact || ((shi - slo) <= MERGE_TOL);
    float sms = exact ? shi : (0.5f * (slo + shi));

    // ---- Main chunk: 32 float4s, Q -> LDS (bank-conflict-free) ----
    {
        constexpr int nmb = (CH / 2) / 4;  // 8 batches
        float4 A[4], Bq[4], C[4];
        #pragma unroll
        for (int j = 0; j < 4; ++j) A[j] = rp[i1 + j];
        #pragma unroll
        for (int j = 0; j < 4; ++j) Bq[j] = rp[i1 + 4 + j];
        for (int k = 0; k < nmb; ++k) {
            int kn = (k + 2 < nmb) ? (k + 2) : (nmb - 1);
            #pragma unroll
            for (int j = 0; j < 4; ++j) C[j] = rp[i1 + 4 * kn + j];
            int tb = 8 * k;
            #pragma unroll
            for (int j = 0; j < 4; ++j) {
                float qa = step(A[j].x, A[j].y, sms, gw, p);
                float qb = step(A[j].z, A[j].w, sms, gw, p);
                lds_q[tb + 2 * j][l]     = qa;
                lds_q[tb + 2 * j + 1][l] = qb;
            }
            #pragma unroll
            for (int j = 0; j < 4; ++j) { A[j] = Bq[j]; Bq[j] = C[j]; }
        }
    }

    st[(size_t)c * B + b] = make_float4(sms, gw, merged ? 1.0f : 0.0f, 0.0f);

    // Q[b,0] from the final carry (jnp.roll wraparound), owned by chunk NC-1.
    float q0 = 0.0f;
    const bool hasq0 = (c == NC - 1);
    if (hasq0) {
        float4 f0 = rp[0];
        float ss = sms, gg = gw;
        q0 = step(f0.x, f0.y, ss, gg, p);
    }

    __syncthreads();                       // lds_q visible across the wave

    // ---- Store phase: coalesced columns. out[b0+j][t1+l] = lds_q[l][j] ----
    const int b0 = b - l;                  // wave base row (B % 64 == 0)
    const int t1 = c * CH;
    const bool skip0 = (c == 0);           // t=0 owned by the wraparound
    for (int j = 0; j < 64; ++j) {
        float v = lds_q[l][j];             // banks (l+j)%32: conflict-free
        if (!skip0 || l > 0) {
            out[(size_t)(b0 + j) * T + t1 + l] = v;
        }
    }
    if (hasq0) orow[0] = q0;
}

// ---------------------------------------------------------------------------
// Fixup: thread per (b, c). Merged -> one coalesced st read, exit. Unmerged
// (rare at W=384) -> walk back to nearest merged predecessor m (chunk 0 is
// always exact => merged), advance store-free through m+1..c-1, recompute
// chunk c exactly with direct out stores. Same semantics as the sequential
// per-row fixup: merged states are accepted as-is.
// ---------------------------------------------------------------------------

template<int T, int NC>
__global__ __launch_bounds__(64)
void hir_fixup(const float* __restrict__ inputs,
               const float* __restrict__ pINSC,  const float* __restrict__ pCOEFF,
               const float* __restrict__ pSQ,    const float* __restrict__ pSMSC,
               const float* __restrict__ pSUB,   const float* __restrict__ pCRAK,
               const float* __restrict__ pRecK,
               float* __restrict__ out, const float4* __restrict__ st, int B)
{
    const int gid = blockIdx.x * 64 + threadIdx.x;
    const int b = gid % B;
    const int c = gid / B;
    if (c >= NC) return;

    float4 sc = st[(size_t)c * B + b];
    if (sc.z != 0.0f) return;              // merged -> nothing to fix

    P p = make_params(pINSC, pCOEFF, pSQ, pSMSC, pSUB, pCRAK, pRecK);
    constexpr int CH = T / NC;

    const float4* __restrict__ rp = (const float4*)(inputs + (size_t)b * (2 * T));
    float* __restrict__ orow = out + (size_t)b * T;

    // Walk back to nearest merged predecessor (c >= 1 here: chunk 0 merged).
    int m = c - 1;
    float4 sm = st[(size_t)m * B + b];
    while (sm.z == 0.0f) { --m; sm = st[(size_t)m * B + b]; }
    float sms = sm.x, gw = sm.y;

    // Advance state through chunks m+1..c-1 (no stores).
    {
        const int ia = ((m + 1) * CH) >> 1;
        const int ib = (c * CH) >> 1;
        for (int i = ia; i < ib; ++i) {
            float4 cur = rp[i];
            stepw(cur.x, cur.y, sms, gw, p);
            stepw(cur.z, cur.w, sms, gw, p);
        }
    }

    // Recompute chunk c exactly, with stores.
    {
        const int i1 = (c * CH) >> 1;
        const int i2 = ((c + 1) * CH) >> 1;
        for (int i = i1; i < i2; ++i) {
            float4 cur = rp[i];
            float qa = step(cur.x, cur.y, sms, gw, p);
            float qb = step(cur.z, cur.w, sms, gw, p);
            ((float2*)orow)[i] = make_float2(qa, qb);
        }
    }

    if (c == NC - 1) {                     // rewrite the t=0 wraparound output
        float4 f0 = rp[0];
        float ss = sms, gg = gw;
        orow[0] = step(f0.x, f0.y, ss, gg, p);
    }
}

// Fallback: monolithic sequential (odd shapes / tiny workspace).
template<int T>
__global__ __launch_bounds__(64, 1)
void hir_scan_kernel(const float* __restrict__ inputs,
                     const float* __restrict__ pINSC,  const float* __restrict__ pCOEFF,
                     const float* __restrict__ pSQ,    const float* __restrict__ pSMSC,
                     const float* __restrict__ pSUB,   const float* __restrict__ pCRAK,
                     const float* __restrict__ pRecK,
                     float* __restrict__ out, int B)
{
    int b = blockIdx.x * blockDim.x + threadIdx.x;
    if (b >= B) return;
    P p = make_params(pINSC, pCOEFF, pSQ, pSMSC, pSUB, pCRAK, pRecK);
    const float4* __restrict__ rp = (const float4*)(inputs + (size_t)b * (2 * T));
    float* __restrict__ orow = out + (size_t)b * T;
    float sms = 0.0f, gw = 0.0f;
    float4 cur = rp[0];
    const float P0 = cur.x, E0 = cur.y;
    constexpr int NI = T / 2;
    for (int i = 0; i < NI; ++i) {
        int ni = (i + 1 < NI) ? (i + 1) : i;
        float4 nxt = rp[ni];
        float qa = step(cur.x, cur.y, sms, gw, p);
        float qb = step(cur.z, cur.w, sms, gw, p);
        if (i == 0) { orow[1] = qb; }
        else        { ((float2*)orow)[i] = make_float2(qa, qb); }
        cur = nxt;
    }
    float ss = sms, gg = gw;
    orow[0] = step(P0, E0, ss, gg, p);
}

extern "C" void kernel_launch(void* const* d_in, const int* in_sizes, int n_in,
                              void* d_out, int out_size, void* d_ws, size_t ws_size,
                              hipStream_t stream) {
    (void)n_in; (void)out_size;
    constexpr int T  = 1024;
    constexpr int NC = 16;    // chunks (CH=64)
    constexpr int W  = 384;   // warm-up: gap ~250*e^(-.0201*384) ~ 0.11 << 0.75
    const float* inputs = (const float*)d_in[0];
    const float* INSC   = (const float*)d_in[1];
    const float* COEFF  = (const float*)d_in[2];
    const float* SQ     = (const float*)d_in[3];
    const float* SMSC   = (const float*)d_in[4];
    const float* SUB    = (const float*)d_in[5];
    const float* CRAK   = (const float*)d_in[6];
    const float* RecK   = (const float*)d_in[7];
    float* out = (float*)d_out;

    int B = in_sizes[0] / (2 * T);            // 4096 for the reference shape
    size_t stBytes = (size_t)B * NC * sizeof(float4);   // 1 MB

    if ((B % 64) == 0 && ws_size >= stBytes) {
        float4* st = (float4*)d_ws;
        long total = (long)B * NC;            // 65536 threads = 1024 waves
        int blocks = (int)((total + 63) / 64);
        hir_pass1<T, NC, W><<<dim3(blocks), dim3(64), 0, stream>>>(
            inputs, INSC, COEFF, SQ, SMSC, SUB, CRAK, RecK, out, st, B);
        hir_fixup<T, NC><<<dim3(blocks), dim3(64), 0, stream>>>(
            inputs, INSC, COEFF, SQ, SMSC, SUB, CRAK, RecK, out, st, B);
        return;
    }

    int blocks = (B + 63) / 64;
    hir_scan_kernel<T><<<dim3(blocks), dim3(64), 0, stream>>>(
        inputs, INSC, COEFF, SQ, SMSC, SUB, CRAK, RecK, out, B);
}

// Round 6
// 121.993 us; speedup vs baseline: 1.2881x; 1.0152x over previous
//
#include <hip/hip_runtime.h>
#include <hip/hip_bf16.h>
#include <math.h>

// HIR rainfall-runoff scan — tolerance-bracketed time-chunking + exact fixup.
//
// V7 changes vs V6 (123.8 us; pass1 50 us @ 42% VALUBusy, fixup <49 us):
//  * Post-mortem: pass1's issue time is ~22 us in EVERY variant (V2/V4/V6);
//    the rest is stall. The depth-2 "rotation" pipeline (A=Bq; Bq=C) copies
//    in-flight loads into registers, forcing s_waitcnt vmcnt(0) at every
//    rotation -> effective prefetch distance was ONE batch (~960 cy), below
//    HBM latency. V4's coalesced loads only saved 7 us => scatter wasn't the
//    main stall; the pipeline depth was.
//  * Fix: 3-buffer unroll-by-3 schedule, zero copies:
//      {load->B2, comp B0}, {load->B0, comp B1}, {load->B1, comp B2}
//    Batch j lives in B[j%3]; loads issue 2 batches (16 steps ~1900 cy)
//    ahead; clamped tail loads always hit already-consumed buffers.
//  * Same pipeline in fixup's advance + recompute loops (V6 had dropped
//    prefetch there entirely -> ~900 cy exposed per float4).
//  * Everything else unchanged from V6 (W=384, MERGE_TOL, LDS
//    store-transpose, 2 kernels) for clean attribution.
//
// Q[b,t] (t>=1) = fluxes from carry entering step t; Q[b,0] uses the FINAL
// carry (jnp.roll wraparound) with t=0 inputs (chunk NC-1 owner writes it).

struct P {
    float INSC, SMSC, RecK, g1, lc, k1, k2, k3, c2;
    // g1=1-RecK, lc=log2(COEFF), k1=SUB/SMSC, k2=CRAK/SMSC, k3=10/SMSC,
    // c2=-SQ/SMSC*log2(e)
};

__device__ __forceinline__ P make_params(const float* pINSC, const float* pCOEFF,
                                         const float* pSQ,   const float* pSMSC,
                                         const float* pSUB,  const float* pCRAK,
                                         const float* pRecK) {
    P p;
    p.INSC      = fminf(fmaxf(pINSC[0]  * 5.0f,   0.5f),   5.0f);
    float COEFF = fminf(fmaxf(pCOEFF[0] * 400.0f, 50.0f),  400.0f);
    float SQ    = fminf(fmaxf(pSQ[0]    * 6.0f,   0.0f),   6.0f);
    p.SMSC      = fminf(fmaxf(pSMSC[0]  * 500.0f, 50.0f),  500.0f);
    float SUB   = fminf(fmaxf(pSUB[0],  0.0f), 1.0f);
    float CRAK  = fminf(fmaxf(pCRAK[0], 0.0f), 1.0f);
    p.RecK      = fminf(fmaxf(pRecK[0]  * 0.3f,   0.003f), 0.3f);
    p.g1 = 1.0f - p.RecK;
    p.lc = log2f(COEFF);
    float inv = 1.0f / p.SMSC;
    p.k1 = SUB * inv;
    p.k2 = CRAK * inv;
    p.k3 = 10.0f * inv;
    p.c2 = (-SQ * inv) * 1.44269504088896340736f;
    return p;
}

// Full step with Q. Critical sms chain: fminf -> fmaf -> exp2f -> fminf ->
// mul -> fmaf. Everything else is off-path.
__device__ __forceinline__ float step(float Prec, float PET, float& sms, float& gw, const P& p) {
    float INT  = fminf(fminf(p.INSC, PET), Prec);
    float INR  = Prec - INT;
    float POT  = PET - INT;
    float S    = fminf(sms, p.SMSC);                 // lower clamp provably slack
    float u    = fmaf(-p.k1, S, 1.0f);
    float v    = fmaf(-p.k2, S, 1.0f);
    float ETS  = fminf(POT, p.k3 * S);
    float SmE  = S - ETS;
    float e    = exp2f(fmaf(p.c2, S, p.lc));         // cap = COEFF*2^(c2*S)
    float RMO  = fminf(INR, e);
    float w    = u * RMO;                            // t2 = RMO - SRUN
    float s2   = fmaf(v, w, SmE);                    // S + SMF - ETS
    float SMF  = v * w;
    float REC  = w - SMF;
    float RECnew = REC + fmaxf(s2 - p.SMSC, 0.0f);
    float BAS  = p.RecK * gw;
    float Q    = (INR - w) + BAS;                    // IRUN + SRUN + BAS
    gw  = fmaf(p.g1, gw, RECnew);
    sms = s2;
    return Q;
}

// Warm-up / state-advance step without Q (single chain, carries gw).
__device__ __forceinline__ void stepw(float Prec, float PET, float& sms, float& gw, const P& p) {
    float INT  = fminf(fminf(p.INSC, PET), Prec);
    float INR  = Prec - INT;
    float POT  = PET - INT;
    float S    = fminf(sms, p.SMSC);
    float u    = fmaf(-p.k1, S, 1.0f);
    float v    = fmaf(-p.k2, S, 1.0f);
    float ETS  = fminf(POT, p.k3 * S);
    float SmE  = S - ETS;
    float e    = exp2f(fmaf(p.c2, S, p.lc));
    float RMO  = fminf(INR, e);
    float w    = u * RMO;
    float s2   = fmaf(v, w, SmE);
    float SMF  = v * w;
    float REC  = w - SMF;
    float RECnew = REC + fmaxf(s2 - p.SMSC, 0.0f);
    gw  = fmaf(p.g1, gw, RECnew);
    sms = s2;
}

// Dual-bracket warm-up step: hi chain carries gw; lo chain is sms-only.
// Shares INT/INR/POT between the chains.
__device__ __forceinline__ void dstep(float Prec, float PET,
                                      float& slo, float& shi, float& gw, const P& p) {
    float INT = fminf(fminf(p.INSC, PET), Prec);
    float INR = Prec - INT;
    float POT = PET - INT;
    {   // hi + gw
        float S    = fminf(shi, p.SMSC);
        float u    = fmaf(-p.k1, S, 1.0f);
        float v    = fmaf(-p.k2, S, 1.0f);
        float ETS  = fminf(POT, p.k3 * S);
        float SmE  = S - ETS;
        float e    = exp2f(fmaf(p.c2, S, p.lc));
        float RMO  = fminf(INR, e);
        float w    = u * RMO;
        float s2   = fmaf(v, w, SmE);
        float SMF  = v * w;
        float REC  = w - SMF;
        float RECnew = REC + fmaxf(s2 - p.SMSC, 0.0f);
        gw  = fmaf(p.g1, gw, RECnew);
        shi = s2;
    }
    {   // lo, sms only
        float S    = fminf(slo, p.SMSC);
        float u    = fmaf(-p.k1, S, 1.0f);
        float v    = fmaf(-p.k2, S, 1.0f);
        float ETS  = fminf(POT, p.k3 * S);
        float SmE  = S - ETS;
        float e    = exp2f(fmaf(p.c2, S, p.lc));
        float RMO  = fminf(INR, e);
        float w    = u * RMO;
        slo = fmaf(v, w, SmE);
    }
}

#define MERGE_TOL 0.75f

// ---------------------------------------------------------------------------
// 3-buffer, 4-float4-batch software pipeline (distance-2, no register copies).
// Ambient names used by the macros: bp (const float4* batch base), B0/B1/B2
// (float4[4] buffers), plus whatever state the CB compute macro references.
// Invariant: batch j's data is in B[j%3]; the load for batch j+2 is issued in
// batch j's slot. Clamped tail loads always target already-consumed buffers.
// ---------------------------------------------------------------------------

#define LB(DST, K, NB) do { int _kn = (K) < (NB) ? (K) : (NB) - 1;              \
    _Pragma("unroll") for (int _q = 0; _q < 4; ++_q) DST[_q] = bp[4 * _kn + _q]; } while (0)

#define PIPE3(NB, CB) do { if ((NB) > 0) {                                      \
    LB(B0, 0, (NB)); LB(B1, 1, (NB));                                           \
    int _j = 0;                                                                 \
    for (; _j + 3 <= (NB); _j += 3) {                                           \
        LB(B2, _j + 2, (NB)); CB(B0, _j);                                       \
        LB(B0, _j + 3, (NB)); CB(B1, _j + 1);                                   \
        LB(B1, _j + 4, (NB)); CB(B2, _j + 2);                                   \
    }                                                                           \
    if (_j < (NB)) { LB(B2, _j + 2, (NB)); CB(B0, _j); ++_j;                    \
        if (_j < (NB)) { LB(B0, _j + 2, (NB)); CB(B1, _j); } }                  \
} } while (0)

// Compute-batch macros (8 steps per batch).
#define CBW(BUF, J) do { _Pragma("unroll") for (int _m = 0; _m < 4; ++_m) {     \
    stepw(BUF[_m].x, BUF[_m].y, shi, gw, p);                                    \
    stepw(BUF[_m].z, BUF[_m].w, shi, gw, p); } } while (0)

#define CBD(BUF, J) do { _Pragma("unroll") for (int _m = 0; _m < 4; ++_m) {     \
    dstep(BUF[_m].x, BUF[_m].y, slo, shi, gw, p);                               \
    dstep(BUF[_m].z, BUF[_m].w, slo, shi, gw, p); } } while (0)

#define CBM(BUF, J) do { int _tb = 8 * (J);                                     \
    _Pragma("unroll") for (int _m = 0; _m < 4; ++_m) {                          \
    float _qa = step(BUF[_m].x, BUF[_m].y, sms, gw, p);                         \
    float _qb = step(BUF[_m].z, BUF[_m].w, sms, gw, p);                         \
    lds_q[_tb + 2 * _m][l] = _qa; lds_q[_tb + 2 * _m + 1][l] = _qb; } } while (0)

#define CBF(BUF, J) do { _Pragma("unroll") for (int _m = 0; _m < 4; ++_m) {     \
    float _qa = step(BUF[_m].x, BUF[_m].y, sms, gw, p);                         \
    float _qb = step(BUF[_m].z, BUF[_m].w, sms, gw, p);                         \
    orow2[ib0 + 4 * (J) + _m] = make_float2(_qa, _qb); } } while (0)

// ---------------------------------------------------------------------------
// Pass 1: one thread per (b, c); lanes = 64 consecutive b, c wave-uniform.
// Q buffered in LDS and written coalesced (store-transpose).
// ---------------------------------------------------------------------------

template<int T, int NC, int W>
__global__ __launch_bounds__(64, 1)
void hir_pass1(const float* __restrict__ inputs,
               const float* __restrict__ pINSC,  const float* __restrict__ pCOEFF,
               const float* __restrict__ pSQ,    const float* __restrict__ pSMSC,
               const float* __restrict__ pSUB,   const float* __restrict__ pCRAK,
               const float* __restrict__ pRecK,
               float* __restrict__ out, float4* __restrict__ st, int B)
{
    __shared__ float lds_q[64][65];        // [t_local][lane], +1 pad: bank-free
    const int l   = threadIdx.x;
    const int gid = blockIdx.x * 64 + l;
    const int b = gid % B;                 // consecutive lanes -> consecutive rows
    const int c = gid / B;                 // wave-uniform (B % 64 == 0)
    if (c >= NC) return;                   // never taken for the exact grid

    P p = make_params(pINSC, pCOEFF, pSQ, pSMSC, pSUB, pCRAK, pRecK);

    const float4* __restrict__ rp = (const float4*)(inputs + (size_t)b * (2 * T));
    float* __restrict__ orow = out + (size_t)b * T;

    constexpr int CH = T / NC;             // 64 steps
    const int i1 = (c * CH) >> 1;          // first main float4 index
    int i0 = i1 - (W >> 1);                // warm-up start (W/2 float4s)
    const bool exact = (i0 <= 0);
    if (i0 < 0) i0 = 0;

    float slo = 0.0f, shi = exact ? 0.0f : p.SMSC, gw = 0.0f;
    float4 B0[4], B1[4], B2[4];

    // ---- Warm-up: pipelined batches (8 steps each), wave-uniform branch ----
    {
        const int nb = (i1 - i0) >> 2;     // multiple of 4 (or 0 for c==0)
        const float4* bp = rp + i0;
        if (exact) {
            PIPE3(nb, CBW);                // advances shi (true chain)
            slo = shi;
        } else {
            PIPE3(nb, CBD);                // dual bracket chains
        }
    }
    const bool merged = exact || ((shi - slo) <= MERGE_TOL);
    float sms = exact ? shi : (0.5f * (slo + shi));

    // ---- Main chunk: 8 batches, Q -> LDS (bank-conflict-free) ----
    {
        const float4* bp = rp + i1;
        PIPE3(8, CBM);
    }

    st[(size_t)c * B + b] = make_float4(sms, gw, merged ? 1.0f : 0.0f, 0.0f);

    // Q[b,0] from the final carry (jnp.roll wraparound), owned by chunk NC-1.
    float q0 = 0.0f;
    const bool hasq0 = (c == NC - 1);
    if (hasq0) {
        float4 f0 = rp[0];
        float ss = sms, gg = gw;
        q0 = step(f0.x, f0.y, ss, gg, p);
    }

    __syncthreads();                       // lds_q visible across the wave

    // ---- Store phase: coalesced columns. out[b0+j][t1+l] = lds_q[l][j] ----
    const int b0 = b - l;                  // wave base row (B % 64 == 0)
    const int t1 = c * CH;
    const bool skip0 = (c == 0);           // t=0 owned by the wraparound
    for (int j = 0; j < 64; ++j) {
        float v = lds_q[l][j];             // banks (l+j)%32: conflict-free
        if (!skip0 || l > 0) {
            out[(size_t)(b0 + j) * T + t1 + l] = v;
        }
    }
    if (hasq0) orow[0] = q0;
}

// ---------------------------------------------------------------------------
// Fixup: thread per (b, c). Merged -> one coalesced st read, exit. Unmerged
// -> walk back to nearest merged predecessor m (chunk 0 is always exact =>
// merged), advance store-free through m+1..c-1, recompute chunk c exactly
// with direct out stores. Both loops use the distance-2 pipeline (V6 had
// no prefetch here: ~900 cy exposed per float4). Same semantics as the
// sequential per-row fixup: merged states are accepted as-is.
// ---------------------------------------------------------------------------

template<int T, int NC>
__global__ __launch_bounds__(64)
void hir_fixup(const float* __restrict__ inputs,
               const float* __restrict__ pINSC,  const float* __restrict__ pCOEFF,
               const float* __restrict__ pSQ,    const float* __restrict__ pSMSC,
               const float* __restrict__ pSUB,   const float* __restrict__ pCRAK,
               const float* __restrict__ pRecK,
               float* __restrict__ out, const float4* __restrict__ st, int B)
{
    const int gid = blockIdx.x * 64 + threadIdx.x;
    const int b = gid % B;
    const int c = gid / B;
    if (c >= NC) return;

    float4 sc = st[(size_t)c * B + b];
    if (sc.z != 0.0f) return;              // merged -> nothing to fix

    P p = make_params(pINSC, pCOEFF, pSQ, pSMSC, pSUB, pCRAK, pRecK);
    constexpr int CH = T / NC;

    const float4* __restrict__ rp = (const float4*)(inputs + (size_t)b * (2 * T));
    float* __restrict__ orow = out + (size_t)b * T;
    float2* __restrict__ orow2 = (float2*)orow;

    // Walk back to nearest merged predecessor (c >= 1 here: chunk 0 merged).
    int m = c - 1;
    float4 sm = st[(size_t)m * B + b];
    while (sm.z == 0.0f) { --m; sm = st[(size_t)m * B + b]; }
    float sms = sm.x, gw = sm.y;

    float4 B0[4], B1[4], B2[4];

    // Advance state through chunks m+1..c-1 (no stores), pipelined.
    {
        const int ia = ((m + 1) * CH) >> 1;
        const int ibx = (c * CH) >> 1;
        const int nb = (ibx - ia) >> 2;    // multiple of 8 (or 0)
        const float4* bp = rp + ia;
        float& shi = sms;                  // CBW advances "shi"
        PIPE3(nb, CBW);
    }

    // Recompute chunk c exactly, with stores, pipelined.
    {
        const int ib0 = (c * CH) >> 1;     // float2 output base index
        const float4* bp = rp + ib0;
        PIPE3(8, CBF);
    }

    if (c == NC - 1) {                     // rewrite the t=0 wraparound output
        float4 f0 = rp[0];
        float ss = sms, gg = gw;
        orow[0] = step(f0.x, f0.y, ss, gg, p);
    }
}

// Fallback: monolithic sequential (odd shapes / tiny workspace).
template<int T>
__global__ __launch_bounds__(64, 1)
void hir_scan_kernel(const float* __restrict__ inputs,
                     const float* __restrict__ pINSC,  const float* __restrict__ pCOEFF,
                     const float* __restrict__ pSQ,    const float* __restrict__ pSMSC,
                     const float* __restrict__ pSUB,   const float* __restrict__ pCRAK,
                     const float* __restrict__ pRecK,
                     float* __restrict__ out, int B)
{
    int b = blockIdx.x * blockDim.x + threadIdx.x;
    if (b >= B) return;
    P p = make_params(pINSC, pCOEFF, pSQ, pSMSC, pSUB, pCRAK, pRecK);
    const float4* __restrict__ rp = (const float4*)(inputs + (size_t)b * (2 * T));
    float* __restrict__ orow = out + (size_t)b * T;
    float sms = 0.0f, gw = 0.0f;
    float4 cur = rp[0];
    const float P0 = cur.x, E0 = cur.y;
    constexpr int NI = T / 2;
    for (int i = 0; i < NI; ++i) {
        int ni = (i + 1 < NI) ? (i + 1) : i;
        float4 nxt = rp[ni];
        float qa = step(cur.x, cur.y, sms, gw, p);
        float qb = step(cur.z, cur.w, sms, gw, p);
        if (i == 0) { orow[1] = qb; }
        else        { ((float2*)orow)[i] = make_float2(qa, qb); }
        cur = nxt;
    }
    float ss = sms, gg = gw;
    orow[0] = step(P0, E0, ss, gg, p);
}

extern "C" void kernel_launch(void* const* d_in, const int* in_sizes, int n_in,
                              void* d_out, int out_size, void* d_ws, size_t ws_size,
                              hipStream_t stream) {
    (void)n_in; (void)out_size;
    constexpr int T  = 1024;
    constexpr int NC = 16;    // chunks (CH=64)
    constexpr int W  = 384;   // warm-up: gap ~250*e^(-.0201*384) ~ 0.11 << 0.75
    const float* inputs = (const float*)d_in[0];
    const float* INSC   = (const float*)d_in[1];
    const float* COEFF  = (const float*)d_in[2];
    const float* SQ     = (const float*)d_in[3];
    const float* SMSC   = (const float*)d_in[4];
    const float* SUB    = (const float*)d_in[5];
    const float* CRAK   = (const float*)d_in[6];
    const float* RecK   = (const float*)d_in[7];
    float* out = (float*)d_out;

    int B = in_sizes[0] / (2 * T);            // 4096 for the reference shape
    size_t stBytes = (size_t)B * NC * sizeof(float4);   // 1 MB

    if ((B % 64) == 0 && ws_size >= stBytes) {
        float4* st = (float4*)d_ws;
        long total = (long)B * NC;            // 65536 threads = 1024 waves
        int blocks = (int)((total + 63) / 64);
        hir_pass1<T, NC, W><<<dim3(blocks), dim3(64), 0, stream>>>(
            inputs, INSC, COEFF, SQ, SMSC, SUB, CRAK, RecK, out, st, B);
        hir_fixup<T, NC><<<dim3(blocks), dim3(64), 0, stream>>>(
            inputs, INSC, COEFF, SQ, SMSC, SUB, CRAK, RecK, out, st, B);
        return;
    }

    int blocks = (B + 63) / 64;
    hir_scan_kernel<T><<<dim3(blocks), dim3(64), 0, stream>>>(
        inputs, INSC, COEFF, SQ, SMSC, SUB, CRAK, RecK, out, B);
}